// Round 18
// baseline (552.749 us; speedup 1.0000x reference)
//
#include <hip/hip_runtime.h>
#include <math.h>

#define B_ 4
#define N_ 1024
#define C_ 1024
#define H_ 16
#define HD_ 64

typedef float f32x2 __attribute__((ext_vector_type(2)));
typedef float f32x4 __attribute__((ext_vector_type(4)));
typedef short bf16x8 __attribute__((ext_vector_type(8)));

__device__ __forceinline__ unsigned short f2bf(float v) {   // RNE f32->bf16
    unsigned u = __float_as_uint(v);
    u += 0x7FFFu + ((u >> 16) & 1u);
    return (unsigned short)(u >> 16);
}

__device__ __forceinline__ float bf2f(unsigned short h) {
    return __uint_as_float(((unsigned)h) << 16);
}

__device__ __forceinline__ float fast_exp2f(float x) {
#if __has_builtin(__builtin_amdgcn_exp2f)
    return __builtin_amdgcn_exp2f(x);   // v_exp_f32, ~1 ulp
#else
    return exp2f(x);
#endif
}

// ---------------------------------------------------------------------------
// ERROR MODEL — FROZEN as of r15 (absmax 96 vs threshold 97.28, deterministic):
//   - PATCH softmax: f32 HW exp2 + split-bf16 MFMA q,k (4 products).
//   - POS softmax: f64 dist+exp chain (mandatory).
//   - EXACT S path: f64 Vall collapse.
//   - DAMPED paths: PV/v/proj bf16 MFMA.
//   All changes must be BIT-IDENTICAL. absmax must read exactly 96.
// PERF MODEL (r16/r17 lesson): attn is VALU-issue-bound (VALU ~50%, occupancy
//   attempts null). r18: the f64 dist chain (14 ops, longest serial dep) was
//   recomputed 16x (once per h-block) — h-independent. Precompute dist[b][n][m]
//   f64 with the IDENTICAL instruction sequence (bit-identical), attn loads it.
//   dist (2 batches = 16.78MB) overlays dead xhi/xlo; attn runs in 2 half-batch
//   passes. attn base = r16 (QBLK16, best).
// ---------------------------------------------------------------------------

// fast f64 exp for |a| <= ~16: range-reduce + deg-8 Taylor. rel err ~3e-10.
__device__ __forceinline__ double fast_exp64(double a) {
    const double LOG2E = 1.4426950408889634074;
    const double LN2HI = 6.93147180369123816490e-01;
    const double LN2LO = 1.90821492927058770002e-10;
    const double MAGIC = 6755399441055744.0;   // 1.5 * 2^52
    double t     = a * LOG2E;
    double shift = t + MAGIC;
    int    n     = (int)__double_as_longlong(shift);
    double nd    = shift - MAGIC;
    double f     = __fma_rn(nd, -LN2HI, a);
    f            = __fma_rn(nd, -LN2LO, f);
    double p = 2.4801587301587301587e-05;
    p = __fma_rn(p, f, 1.9841269841269841270e-04);
    p = __fma_rn(p, f, 1.3888888888888888889e-03);
    p = __fma_rn(p, f, 8.3333333333333333333e-03);
    p = __fma_rn(p, f, 4.1666666666666666667e-02);
    p = __fma_rn(p, f, 1.6666666666666666667e-01);
    p = __fma_rn(p, f, 5.0e-01);
    p = __fma_rn(p, f, 1.0);
    p = __fma_rn(p, f, 1.0);
    return p * __longlong_as_double(((long long)(1023 + n)) << 52);
}

// ---------------------------------------------------------------------------
// dist[b][n][m] precompute — instruction sequence IDENTICAL to the former
// in-attn chain (bit-identical f64 result). 2 batches per pass.
// ---------------------------------------------------------------------------
__global__ __launch_bounds__(256)
void dist_kernel(const float* __restrict__ coord, double* __restrict__ dist,
                 int bbase)
{
    const int m = blockIdx.x * 256 + threadIdx.x;
    const int n = blockIdx.y;
    const int z = blockIdx.z;
    const int b = bbase + z;
    const float* cq = coord + ((size_t)b * N_ + n) * 3;
    const float* cm = coord + ((size_t)b * N_ + m) * 3;
    const double dx = (double)cq[0] - (double)cm[0];
    const double dy = (double)cq[1] - (double)cm[1];
    const double dz = (double)cq[2] - (double)cm[2];
    const double r2 = __fma_rn(dx, dx, __fma_rn(dy, dy, dz * dz));
    const double y0 = (double)rsqrtf((float)r2);
    const double y1 = y0 * __fma_rn(-0.5 * r2, y0 * y0, 1.5);
    dist[((size_t)z * N_ + n) * N_ + m] = (r2 > 0.0) ? r2 * y1 : 0.0;
}

// ---------------------------------------------------------------------------
// f32 -> bf16 bulk convert
// ---------------------------------------------------------------------------
__global__ __launch_bounds__(256)
void cvt_bf16_kernel(const float* __restrict__ src, unsigned short* __restrict__ dst, int n)
{
    const int i = (blockIdx.x * 256 + threadIdx.x) * 8;
    if (i >= n) return;
    const float4 a = *reinterpret_cast<const float4*>(&src[i]);
    const float4 b = *reinterpret_cast<const float4*>(&src[i + 4]);
    unsigned short pk[8];
    pk[0] = f2bf(a.x); pk[1] = f2bf(a.y); pk[2] = f2bf(a.z); pk[3] = f2bf(a.w);
    pk[4] = f2bf(b.x); pk[5] = f2bf(b.y); pk[6] = f2bf(b.z); pk[7] = f2bf(b.w);
    *reinterpret_cast<bf16x8*>(&dst[i]) = *reinterpret_cast<bf16x8*>(pk);
}

// ---------------------------------------------------------------------------
// f32 -> (hi, lo) bf16 split
// ---------------------------------------------------------------------------
__global__ __launch_bounds__(256)
void cvt_split_kernel(const float* __restrict__ src,
                      unsigned short* __restrict__ hi,
                      unsigned short* __restrict__ lo, int n)
{
    const int i = (blockIdx.x * 256 + threadIdx.x) * 8;
    if (i >= n) return;
    unsigned short ph[8], pl[8];
    #pragma unroll
    for (int j = 0; j < 8; ++j) {
        const float v = src[i + j];
        const unsigned short h = f2bf(v);
        ph[j] = h;
        pl[j] = f2bf(v - bf2f(h));
    }
    *reinterpret_cast<bf16x8*>(&hi[i]) = *reinterpret_cast<bf16x8*>(ph);
    *reinterpret_cast<bf16x8*>(&lo[i]) = *reinterpret_cast<bf16x8*>(pl);
}

// ---------------------------------------------------------------------------
// Split-bf16 MFMA GEMM for q,k. r15-validated, unchanged.
// ---------------------------------------------------------------------------
__global__ __launch_bounds__(256)
void qk_split_kernel(const unsigned short* __restrict__ Ahi,
                     const unsigned short* __restrict__ Alo,
                     const unsigned short* __restrict__ Bhi,
                     const unsigned short* __restrict__ Blo,
                     float* __restrict__ outq,
                     float* __restrict__ outk,
                     int M, int O, int K)
{
    __shared__ unsigned short Ash[128][40];
    __shared__ unsigned short Asl[128][40];
    __shared__ unsigned short Bsh[64][40];
    __shared__ unsigned short Bsl[64][40];

    const int t  = threadIdx.x;
    const int w  = t >> 6;
    const int l  = t & 63;
    const int o0 = blockIdx.x * 64;
    const int m0 = blockIdx.y * 128;

    f32x4 acc[2][4];
    #pragma unroll
    for (int r = 0; r < 2; ++r)
        #pragma unroll
        for (int c = 0; c < 4; ++c) acc[r][c] = (f32x4){0.f, 0.f, 0.f, 0.f};

    const int ar = t >> 1, aseg = t & 1;
    const int br = t >> 2, bseg = t & 3;
    const int fr = l & 15, kg = l >> 4;

    for (int k0 = 0; k0 < K; k0 += 32) {
        const size_t abase = (size_t)(m0 + ar) * K + k0 + aseg * 16;
        const size_t bbase = (size_t)(o0 + br) * K + k0 + bseg * 8;
        const bf16x8 ah0 = *reinterpret_cast<const bf16x8*>(&Ahi[abase]);
        const bf16x8 ah1 = *reinterpret_cast<const bf16x8*>(&Ahi[abase + 8]);
        const bf16x8 al0 = *reinterpret_cast<const bf16x8*>(&Alo[abase]);
        const bf16x8 al1 = *reinterpret_cast<const bf16x8*>(&Alo[abase + 8]);
        const bf16x8 bh0 = *reinterpret_cast<const bf16x8*>(&Bhi[bbase]);
        const bf16x8 bl0 = *reinterpret_cast<const bf16x8*>(&Blo[bbase]);
        __syncthreads();
        *reinterpret_cast<bf16x8*>(&Ash[ar][aseg * 16])     = ah0;
        *reinterpret_cast<bf16x8*>(&Ash[ar][aseg * 16 + 8]) = ah1;
        *reinterpret_cast<bf16x8*>(&Asl[ar][aseg * 16])     = al0;
        *reinterpret_cast<bf16x8*>(&Asl[ar][aseg * 16 + 8]) = al1;
        *reinterpret_cast<bf16x8*>(&Bsh[br][bseg * 8])      = bh0;
        *reinterpret_cast<bf16x8*>(&Bsl[br][bseg * 8])      = bl0;
        __syncthreads();

        bf16x8 bfh[4], bfl[4];
        #pragma unroll
        for (int c = 0; c < 4; ++c) {
            bfh[c] = *reinterpret_cast<const bf16x8*>(&Bsh[c * 16 + fr][kg * 8]);
            bfl[c] = *reinterpret_cast<const bf16x8*>(&Bsl[c * 16 + fr][kg * 8]);
        }
        #pragma unroll
        for (int r = 0; r < 2; ++r) {
            const bf16x8 afh = *reinterpret_cast<const bf16x8*>(&Ash[w * 32 + r * 16 + fr][kg * 8]);
            const bf16x8 afl = *reinterpret_cast<const bf16x8*>(&Asl[w * 32 + r * 16 + fr][kg * 8]);
            #pragma unroll
            for (int c = 0; c < 4; ++c) {
                f32x4 a = acc[r][c];
                a = __builtin_amdgcn_mfma_f32_16x16x32_bf16(afh, bfh[c], a, 0, 0, 0);
                a = __builtin_amdgcn_mfma_f32_16x16x32_bf16(afh, bfl[c], a, 0, 0, 0);
                a = __builtin_amdgcn_mfma_f32_16x16x32_bf16(afl, bfh[c], a, 0, 0, 0);
                a = __builtin_amdgcn_mfma_f32_16x16x32_bf16(afl, bfl[c], a, 0, 0, 0);
                acc[r][c] = a;
            }
        }
    }

    #pragma unroll
    for (int c = 0; c < 4; ++c) {
        int oo = o0 + c * 16 + fr;
        float* dst = (oo < 1024) ? outq : outk;
        oo &= 1023;
        const int hh = oo >> 6, d0 = oo & 63;
        #pragma unroll
        for (int r = 0; r < 2; ++r) {
            #pragma unroll
            for (int j = 0; j < 4; ++j) {
                const int m = m0 + w * 32 + r * 16 + kg * 4 + j;
                const int bb_ = m >> 10, n = m & 1023;
                dst[((((size_t)bb_ * H_) + hh) * N_ + n) * HD_ + d0] = acc[r][c][j];
            }
        }
    }
}

// ---------------------------------------------------------------------------
// bf16 MFMA GEMM (damped paths). Validated r13, unchanged.
// ---------------------------------------------------------------------------
template<int OUT_BF16>
__global__ __launch_bounds__(256)
void mfma_gemm_kernel(const unsigned short* __restrict__ A,
                      const unsigned short* __restrict__ Bw,
                      const float* __restrict__ bias,
                      float* __restrict__ outF,
                      unsigned short* __restrict__ outB,
                      int M, int O, int K)
{
    __shared__ unsigned short As[128][40];
    __shared__ unsigned short Bs[64][40];

    const int t  = threadIdx.x;
    const int w  = t >> 6;
    const int l  = t & 63;
    const int o0 = blockIdx.x * 64;
    const int m0 = blockIdx.y * 128;
    const size_t zoff = (size_t)blockIdx.z * 1048576;
    Bw += zoff;

    f32x4 acc[2][4];
    #pragma unroll
    for (int r = 0; r < 2; ++r)
        #pragma unroll
        for (int c = 0; c < 4; ++c) acc[r][c] = (f32x4){0.f, 0.f, 0.f, 0.f};

    const int ar = t >> 1, aseg = t & 1;
    const int br = t >> 2, bseg = t & 3;
    const int fr = l & 15, kg = l >> 4;

    for (int k0 = 0; k0 < K; k0 += 32) {
        const bf16x8 a0 = *reinterpret_cast<const bf16x8*>(&A[(size_t)(m0 + ar) * K + k0 + aseg * 16]);
        const bf16x8 a1 = *reinterpret_cast<const bf16x8*>(&A[(size_t)(m0 + ar) * K + k0 + aseg * 16 + 8]);
        const bf16x8 b0 = *reinterpret_cast<const bf16x8*>(&Bw[(size_t)(o0 + br) * K + k0 + bseg * 8]);
        __syncthreads();
        *reinterpret_cast<bf16x8*>(&As[ar][aseg * 16])     = a0;
        *reinterpret_cast<bf16x8*>(&As[ar][aseg * 16 + 8]) = a1;
        *reinterpret_cast<bf16x8*>(&Bs[br][bseg * 8])      = b0;
        __syncthreads();

        bf16x8 bfr[4];
        #pragma unroll
        for (int c = 0; c < 4; ++c)
            bfr[c] = *reinterpret_cast<const bf16x8*>(&Bs[c * 16 + fr][kg * 8]);
        #pragma unroll
        for (int r = 0; r < 2; ++r) {
            const bf16x8 af = *reinterpret_cast<const bf16x8*>(&As[w * 32 + r * 16 + fr][kg * 8]);
            #pragma unroll
            for (int c = 0; c < 4; ++c)
                acc[r][c] = __builtin_amdgcn_mfma_f32_16x16x32_bf16(af, bfr[c], acc[r][c], 0, 0, 0);
        }
    }

    #pragma unroll
    for (int c = 0; c < 4; ++c) {
        const int col = o0 + c * 16 + fr;
        const float bv = (OUT_BF16 == 0) ? bias[col] : 0.f;
        #pragma unroll
        for (int r = 0; r < 2; ++r) {
            #pragma unroll
            for (int j = 0; j < 4; ++j) {
                const int row = m0 + w * 32 + r * 16 + kg * 4 + j;
                const float v = acc[r][c][j] + bv;
                if (OUT_BF16)
                    outB[zoff + (size_t)row * O + col] = f2bf(v);
                else
                    outF[(size_t)row * O + col] = v;
            }
        }
    }
}

// ---------------------------------------------------------------------------
__global__ void wsum_kernel(const float* __restrict__ W_v, double* __restrict__ wsh)
{
    const int k = blockIdx.x * 256 + threadIdx.x;
    const int h = blockIdx.y;
    double s = 0.0;
    #pragma unroll 8
    for (int d = 0; d < 64; ++d) s += (double)W_v[(size_t)(h * 64 + d) * C_ + k];
    wsh[h * C_ + k] = s;
}

__global__ __launch_bounds__(256)
void vall_kernel(const float* __restrict__ x, const double* __restrict__ wsh,
                 double* __restrict__ Vall)
{
    __shared__ double ws_s[1024];
    const int h = blockIdx.y, b = blockIdx.z;
    const int m = blockIdx.x * 256 + threadIdx.x;
    for (int i = threadIdx.x; i < 1024; i += 256) ws_s[i] = wsh[h * C_ + i];
    __syncthreads();
    const float* xr = x + ((size_t)b * N_ + m) * C_;
    double acc = 0.0;
    #pragma unroll 8
    for (int kk = 0; kk < 1024; ++kk) acc += (double)xr[kk] * ws_s[kk];
    Vall[((size_t)b * H_ + h) * N_ + m] = acc;
}

// ---------------------------------------------------------------------------
// Fused attention r18 = r16 (QBLK16, best) with the dist chain replaced by a
// bit-identical precomputed-dist load. All other math unchanged.
// blockIdx.z in {0,1}; b = bbase + z; dist buffer holds 2 batches.
// ---------------------------------------------------------------------------
__device__ __forceinline__ f32x2 pk_fma(f32x2 a, f32x2 b, f32x2 c) {
#if __has_builtin(__builtin_elementwise_fma)
    return __builtin_elementwise_fma(a, b, c);
#else
    f32x2 r; r.x = fmaf(a.x, b.x, c.x); r.y = fmaf(a.y, b.y, c.y); return r;
#endif
}

__global__ __launch_bounds__(256)
void attn_kernel(const float* __restrict__ q,
                 const float* __restrict__ k,
                 const unsigned short* __restrict__ vtb,
                 const double* __restrict__ Vall,
                 const double* __restrict__ dist,   // [2][N][N] (z-local)
                 const float* __restrict__ W_pos,
                 const float* __restrict__ gating,
                 unsigned short* __restrict__ attnB,
                 int bbase)
{
    __shared__ float4 Qs4[16][16];                          // 4096B
    __shared__ float4 Kt4[64][16];                          // 16384B
    __shared__ __align__(16) unsigned short ptB[16 * 64];   // 2048B (epi alias)
    __shared__ __align__(16) unsigned short qtB[16 * 64];   // 2048B
    __shared__ __align__(16) unsigned short VtB[2][64 * 64];// 16384B

    const int t  = threadIdx.x;
    const int w  = t >> 6;
    const int l  = t & 63;
    const int n0 = blockIdx.x * 16;
    const int h  = blockIdx.y;
    const int z  = blockIdx.z;
    const int b  = bbase + z;
    const size_t bhN = ((size_t)b * H_ + h) * N_;

    const int sr0 = t >> 4;
    const int sc  = t & 15;
    const int vd  = t >> 2;
    const int vkc = (t & 3) * 16;
    const unsigned short* vrow = vtb + (((size_t)b * H_ + h) * 64 + vd) * N_;
    const int vswz = (vd & 7) << 4;

    // per-wave dist row pointers (rows w+4i, z-local batch)
    const double* dr0 = dist + ((size_t)z * N_ + n0 + w     ) * N_;
    const double* dr1 = dist + ((size_t)z * N_ + n0 + w + 4 ) * N_;
    const double* dr2 = dist + ((size_t)z * N_ + n0 + w + 8 ) * N_;
    const double* dr3 = dist + ((size_t)z * N_ + n0 + w + 12) * N_;

    Qs4[t >> 4][t & 15] = reinterpret_cast<const float4*>(q + (bhN + n0) * HD_)[t];
    const double w4hd = (double)W_pos[h * 4 + 3];
    const double ghd  = 1.0 / (1.0 + exp(-(double)gating[h]));

    double sp[4], sq[4], spv[4], sqv[4];
    f32x4 accP = {0.f, 0.f, 0.f, 0.f};
    f32x4 accQ = {0.f, 0.f, 0.f, 0.f};
    #pragma unroll
    for (int i = 0; i < 4; ++i) { sp[i] = 0.0; sq[i] = 0.0; spv[i] = 0.0; sqv[i] = 0.0; }

    {
        const float4* kb4 = reinterpret_cast<const float4*>(k + bhN * HD_);
        #pragma unroll
        for (int i = 0; i < 4; ++i)
            Kt4[sr0 + i * 16][sc ^ ((sr0 + i * 16) & 15)] = kb4[t + i * 256];
        const bf16x8 v0 = *reinterpret_cast<const bf16x8*>(vrow + vkc);
        const bf16x8 v1 = *reinterpret_cast<const bf16x8*>(vrow + vkc + 8);
        char* vb = reinterpret_cast<char*>(&VtB[0][0]);
        *reinterpret_cast<bf16x8*>(vb + ((vd * 128 + vkc * 2)      ^ vswz)) = v0;
        *reinterpret_cast<bf16x8*>(vb + ((vd * 128 + vkc * 2 + 16) ^ vswz)) = v1;
    }
    double Vm = Vall[bhN + l];
    double dv0 = dr0[l], dv1 = dr1[l], dv2 = dr2[l], dv3 = dr3[l];
    __syncthreads();

    for (int t16 = 0; t16 < 16; ++t16) {
        const int m0   = t16 * 64;
        const int vcur = t16 & 1;

        // ---- (1) prefetch next tile
        float4 st0, st1, st2, st3;
        bf16x8 sv0, sv1;
        double VmN = 0.0, dN0 = 0.0, dN1 = 0.0, dN2 = 0.0, dN3 = 0.0;
        if (t16 < 15) {
            const float4* kb4 = reinterpret_cast<const float4*>(k + (bhN + m0 + 64) * HD_);
            st0 = kb4[t];
            st1 = kb4[t + 256];
            st2 = kb4[t + 512];
            st3 = kb4[t + 768];
            sv0 = *reinterpret_cast<const bf16x8*>(vrow + m0 + 64 + vkc);
            sv1 = *reinterpret_cast<const bf16x8*>(vrow + m0 + 64 + vkc + 8);
            VmN = Vall[bhN + m0 + 64 + l];
            dN0 = dr0[m0 + 64 + l];
            dN1 = dr1[m0 + 64 + l];
            dN2 = dr2[m0 + 64 + l];
            dN3 = dr3[m0 + 64 + l];
        }

        // ---- (2) QK^T packed f32 (rows w+4i, column m0+l)
        f32x2 dot2[4][2];
        #pragma unroll
        for (int i = 0; i < 4; ++i) {
            dot2[i][0] = (f32x2){0.f, 0.f};
            dot2[i][1] = (f32x2){0.f, 0.f};
        }
        #pragma unroll
        for (int d4 = 0; d4 < 16; ++d4) {
            const float4 kt = Kt4[l][d4 ^ (l & 15)];
            const int g = d4 >> 3;
            const f32x2 kxy = {kt.x, kt.y};
            const f32x2 kzw = {kt.z, kt.w};
            #pragma unroll
            for (int i = 0; i < 4; ++i) {
                const float4 q4 = Qs4[w + 4 * i][d4];
                dot2[i][g] = pk_fma(kxy, (f32x2){q4.x, q4.y}, dot2[i][g]);
                dot2[i][g] = pk_fma(kzw, (f32x2){q4.z, q4.w}, dot2[i][g]);
            }
        }

        // ---- (3) weights + f64 S-path (dist loaded, bit-identical chain tail)
        const double dvs[4] = {dv0, dv1, dv2, dv3};
        #pragma unroll
        for (int i = 0; i < 4; ++i) {
            const int r = w + 4 * i;
            const double lgs = (((double)dot2[i][0].x + (double)dot2[i][0].y) +
                                ((double)dot2[i][1].x + (double)dot2[i][1].y));
            const float pf = fast_exp2f((float)(lgs * 0.18033688011112042));  // 0.125*log2(e)
            const double q64 = fast_exp64(dvs[i] * w4hd);
            const int off = (r * 128 + l * 2) ^ ((r & 7) << 4);
            *reinterpret_cast<unsigned short*>(reinterpret_cast<char*>(ptB) + off) = f2bf(pf);
            *reinterpret_cast<unsigned short*>(reinterpret_cast<char*>(qtB) + off) = f2bf((float)q64);
            sp[i]  += (double)pf;
            sq[i]  += q64;
            spv[i] += (double)pf * Vm;
            sqv[i] += q64 * Vm;
        }
        __syncthreads();   // barrier A

        // ---- (4) PV MFMA
        {
            const int r_   = l & 15;
            const int kb_  = l >> 4;
            const int aoff = r_ * 128 + kb_ * 16;
            const int aswz = (r_ & 7) << 4;
            const int dimw = w * 16 + r_;
            const int boff = dimw * 128 + kb_ * 16;
            const int bswz = (dimw & 7) << 4;
            const char* pbase = reinterpret_cast<const char*>(ptB);
            const char* qbase = reinterpret_cast<const char*>(qtB);
            const char* vbase = reinterpret_cast<const char*>(&VtB[vcur][0]);
            #pragma unroll
            for (int kh = 0; kh < 2; ++kh) {
                const bf16x8 afp = *reinterpret_cast<const bf16x8*>(pbase + ((aoff + kh * 64) ^ aswz));
                const bf16x8 afq = *reinterpret_cast<const bf16x8*>(qbase + ((aoff + kh * 64) ^ aswz));
                const bf16x8 bf_ = *reinterpret_cast<const bf16x8*>(vbase + ((boff + kh * 64) ^ bswz));
                accP = __builtin_amdgcn_mfma_f32_16x16x32_bf16(afp, bf_, accP, 0, 0, 0);
                accQ = __builtin_amdgcn_mfma_f32_16x16x32_bf16(afq, bf_, accQ, 0, 0, 0);
            }
        }

        // ---- (5) write staged K/Vt; roll Vm/dist
        if (t16 < 15) {
            Kt4[sr0     ][sc ^ ( sr0       & 15)] = st0;
            Kt4[sr0 + 16][sc ^ ((sr0 + 16) & 15)] = st1;
            Kt4[sr0 + 32][sc ^ ((sr0 + 32) & 15)] = st2;
            Kt4[sr0 + 48][sc ^ ((sr0 + 48) & 15)] = st3;
            char* vb = reinterpret_cast<char*>(&VtB[vcur ^ 1][0]);
            *reinterpret_cast<bf16x8*>(vb + ((vd * 128 + vkc * 2)      ^ vswz)) = sv0;
            *reinterpret_cast<bf16x8*>(vb + ((vd * 128 + vkc * 2 + 16) ^ vswz)) = sv1;
            Vm = VmN; dv0 = dN0; dv1 = dN1; dv2 = dN2; dv3 = dN3;
        }
        __syncthreads();   // barrier B  (frees ptB for epilogue alias)
    }

    // ---- epilogue: per-row w1/w2/S via ptB alias
    double* epi = reinterpret_cast<double*>(ptB);
    #pragma unroll
    for (int i = 0; i < 4; ++i) {
        double vsp = sp[i], vsq = sq[i], vspv = spv[i], vsqv = sqv[i];
        #pragma unroll
        for (int mm = 32; mm >= 1; mm >>= 1) {
            vsp  += __shfl_xor(vsp,  mm);
            vsq  += __shfl_xor(vsq,  mm);
            vspv += __shfl_xor(vspv, mm);
            vsqv += __shfl_xor(vsqv, mm);
        }
        const double w1 = (1.0 - ghd) / vsp;
        const double w2 = ghd / vsq;
        if (l == 0) {
            epi[w + 4 * i]      = w1;
            epi[16 + w + 4 * i] = w2;
            epi[32 + w + 4 * i] = w1 * vspv + w2 * vsqv;   // S
        }
    }
    __syncthreads();
    const int col = h * HD_ + w * 16 + (l & 15);
    #pragma unroll
    for (int j = 0; j < 4; ++j) {
        const int m = 4 * (l >> 4) + j;
        const double a = epi[m] * (double)accP[j] + epi[16 + m] * (double)accQ[j];
        attnB[((size_t)b * N_ + n0 + m) * C_ + col] = f2bf((float)(a / epi[32 + m]));
    }
}

// ---------------------------------------------------------------------------
extern "C" void kernel_launch(void* const* d_in, const int* in_sizes, int n_in,
                              void* d_out, int out_size, void* d_ws, size_t ws_size,
                              hipStream_t stream)
{
    const float* x      = (const float*)d_in[0];
    const float* coord  = (const float*)d_in[1];
    const float* W_qk   = (const float*)d_in[2];
    const float* W_v    = (const float*)d_in[3];
    const float* W_proj = (const float*)d_in[4];
    const float* b_proj = (const float*)d_in[5];
    const float* W_pos  = (const float*)d_in[6];
    // d_in[7] = b_pos (cancels in softmax), d_in[9] = pos_emb (cancels) — unused
    const float* gating = (const float*)d_in[8];

    float* ws   = (float*)d_ws;
    const size_t per = (size_t)B_ * H_ * N_ * HD_;   // 4,194,304 elements
    float*          qb    = ws;                          // 16MB
    float*          kb    = qb + per;                    // 16MB
    unsigned short* attnB = (unsigned short*)(kb + per); // 8MB; hosts Wqk splits pre-attn
    unsigned short* WqkHi = attnB;                       // 4MB
    unsigned short* WqkLo = attnB + 2 * (size_t)C_ * C_; // 4MB
    unsigned short* vtb   = attnB + per;                 // 8MB
    unsigned short* xhi   = vtb + per;                   // 8MB (dead pre-attn)
    unsigned short* xlo   = xhi + per;                   // 8MB (dead pre-attn)
    double*         distB = (double*)xhi;                // 16.78MB overlay (2 batches)
    unsigned short* WvB   = xlo + per;                   // 2MB
    unsigned short* WpB   = WvB + (size_t)C_ * C_;       // 2MB
    double*         wsh   = (double*)(WpB + (size_t)C_ * C_);
    double*         Vall  = wsh + (size_t)H_ * C_;
    float*          out   = (float*)d_out;

    // splits + bf16 conversions
    cvt_split_kernel<<<2048, 256, 0, stream>>>(x, xhi, xlo, (int)per);
    cvt_split_kernel<<<1024, 256, 0, stream>>>(W_qk, WqkHi, WqkLo, 2 * C_ * C_);
    cvt_bf16_kernel<<<512, 256, 0, stream>>>(W_v, WvB, C_ * C_);
    cvt_bf16_kernel<<<512, 256, 0, stream>>>(W_proj, WpB, C_ * C_);

    // exact S-path precomputation (from raw f32 inputs)
    wsum_kernel<<<dim3(4, 16), 256, 0, stream>>>(W_v, wsh);
    vall_kernel<<<dim3(4, 16, 4), 256, 0, stream>>>(x, wsh, Vall);

    // q,k via split-bf16 MFMA
    qk_split_kernel<<<dim3(32, 32), 256, 0, stream>>>(
        xhi, xlo, WqkHi, WqkLo, qb, kb, B_ * N_, 2 * C_, C_);

    // v^T bf16 via MFMA
    mfma_gemm_kernel<1><<<dim3(16, 8, 4), 256, 0, stream>>>(
        WvB, xhi, nullptr, nullptr, vtb, C_, N_, C_);

    // --- half-batch passes: dist (overlays dead xhi/xlo) then attention ---
    dist_kernel<<<dim3(4, 1024, 2), 256, 0, stream>>>(coord, distB, 0);
    attn_kernel<<<dim3(N_ / 16, H_, 2), 256, 0, stream>>>(
        qb, kb, vtb, Vall, distB, W_pos, gating, attnB, 0);

    dist_kernel<<<dim3(4, 1024, 2), 256, 0, stream>>>(coord, distB, 2);
    attn_kernel<<<dim3(N_ / 16, H_, 2), 256, 0, stream>>>(
        qb, kb, vtb, Vall, distB, W_pos, gating, attnB, 2);

    // proj via MFMA
    mfma_gemm_kernel<0><<<dim3(16, 32, 1), 256, 0, stream>>>(
        attnB, WpB, b_proj, out, nullptr, B_ * N_, C_, C_);
}

// Round 19
// 536.168 us; speedup vs baseline: 1.0309x; 1.0309x over previous
//
#include <hip/hip_runtime.h>
#include <math.h>

#define B_ 4
#define N_ 1024
#define C_ 1024
#define H_ 16
#define HD_ 64

typedef float f32x2 __attribute__((ext_vector_type(2)));
typedef float f32x4 __attribute__((ext_vector_type(4)));
typedef short bf16x8 __attribute__((ext_vector_type(8)));

__device__ __forceinline__ unsigned short f2bf(float v) {   // RNE f32->bf16
    unsigned u = __float_as_uint(v);
    u += 0x7FFFu + ((u >> 16) & 1u);
    return (unsigned short)(u >> 16);
}

__device__ __forceinline__ float bf2f(unsigned short h) {
    return __uint_as_float(((unsigned)h) << 16);
}

__device__ __forceinline__ float fast_exp2f(float x) {
#if __has_builtin(__builtin_amdgcn_exp2f)
    return __builtin_amdgcn_exp2f(x);   // v_exp_f32, ~1 ulp
#else
    return exp2f(x);
#endif
}

__device__ __forceinline__ float rdfl(float v) {   // force wave-uniform -> SGPR
    return __uint_as_float(__builtin_amdgcn_readfirstlane(__float_as_uint(v)));
}

// ---------------------------------------------------------------------------
// ERROR MODEL — FROZEN as of r15 (absmax 96 vs threshold 97.28, deterministic):
//   - PATCH softmax: f32 HW exp2 + split-bf16 MFMA q,k (4 products).
//   - POS softmax: f64 dist+exp chain (mandatory, in-kernel).
//   - EXACT S path: f64 Vall collapse.
//   - DAMPED paths: PV/v/proj bf16 MFMA.
//   All changes must be BIT-IDENTICAL. absmax must read exactly 96.
// PERF MODEL:
//   - attn (r16 form, 403us): LDS-issue-bound (~86 LDS instr/wave-tile, 64 =
//     Q broadcasts). Model predicts 370us floor -> at pipe roofline for this
//     shape; QK-MFMA numerically forbidden; restructures regressed (r9/r17/r18).
//   - r19: MFMA GEMMs were HBM-reread-bound (O-tile 64 => A re-read per 64
//     cols). O-tile 64->128 halves HBM traffic; accumulation order per output
//     element unchanged (bit-identical).
// ---------------------------------------------------------------------------

// fast f64 exp for |a| <= ~16: range-reduce + deg-8 Taylor. rel err ~3e-10.
__device__ __forceinline__ double fast_exp64(double a) {
    const double LOG2E = 1.4426950408889634074;
    const double LN2HI = 6.93147180369123816490e-01;
    const double LN2LO = 1.90821492927058770002e-10;
    const double MAGIC = 6755399441055744.0;   // 1.5 * 2^52
    double t     = a * LOG2E;
    double shift = t + MAGIC;
    int    n     = (int)__double_as_longlong(shift);
    double nd    = shift - MAGIC;
    double f     = __fma_rn(nd, -LN2HI, a);
    f            = __fma_rn(nd, -LN2LO, f);
    double p = 2.4801587301587301587e-05;
    p = __fma_rn(p, f, 1.9841269841269841270e-04);
    p = __fma_rn(p, f, 1.3888888888888888889e-03);
    p = __fma_rn(p, f, 8.3333333333333333333e-03);
    p = __fma_rn(p, f, 4.1666666666666666667e-02);
    p = __fma_rn(p, f, 1.6666666666666666667e-01);
    p = __fma_rn(p, f, 5.0e-01);
    p = __fma_rn(p, f, 1.0);
    p = __fma_rn(p, f, 1.0);
    return p * __longlong_as_double(((long long)(1023 + n)) << 52);
}

// ---------------------------------------------------------------------------
// f32 -> bf16 bulk convert
// ---------------------------------------------------------------------------
__global__ __launch_bounds__(256)
void cvt_bf16_kernel(const float* __restrict__ src, unsigned short* __restrict__ dst, int n)
{
    const int i = (blockIdx.x * 256 + threadIdx.x) * 8;
    if (i >= n) return;
    const float4 a = *reinterpret_cast<const float4*>(&src[i]);
    const float4 b = *reinterpret_cast<const float4*>(&src[i + 4]);
    unsigned short pk[8];
    pk[0] = f2bf(a.x); pk[1] = f2bf(a.y); pk[2] = f2bf(a.z); pk[3] = f2bf(a.w);
    pk[4] = f2bf(b.x); pk[5] = f2bf(b.y); pk[6] = f2bf(b.z); pk[7] = f2bf(b.w);
    *reinterpret_cast<bf16x8*>(&dst[i]) = *reinterpret_cast<bf16x8*>(pk);
}

// ---------------------------------------------------------------------------
// f32 -> (hi, lo) bf16 split
// ---------------------------------------------------------------------------
__global__ __launch_bounds__(256)
void cvt_split_kernel(const float* __restrict__ src,
                      unsigned short* __restrict__ hi,
                      unsigned short* __restrict__ lo, int n)
{
    const int i = (blockIdx.x * 256 + threadIdx.x) * 8;
    if (i >= n) return;
    unsigned short ph[8], pl[8];
    #pragma unroll
    for (int j = 0; j < 8; ++j) {
        const float v = src[i + j];
        const unsigned short h = f2bf(v);
        ph[j] = h;
        pl[j] = f2bf(v - bf2f(h));
    }
    *reinterpret_cast<bf16x8*>(&hi[i]) = *reinterpret_cast<bf16x8*>(ph);
    *reinterpret_cast<bf16x8*>(&lo[i]) = *reinterpret_cast<bf16x8*>(pl);
}

// ---------------------------------------------------------------------------
// Split-bf16 MFMA GEMM for q,k. r19: O-tile 128 (halves A re-reads from HBM).
// Per-output accumulation order identical to r15 (bit-identical results).
// ---------------------------------------------------------------------------
__global__ __launch_bounds__(256)
void qk_split_kernel(const unsigned short* __restrict__ Ahi,
                     const unsigned short* __restrict__ Alo,
                     const unsigned short* __restrict__ Bhi,
                     const unsigned short* __restrict__ Blo,
                     float* __restrict__ outq,
                     float* __restrict__ outk,
                     int M, int O, int K)
{
    __shared__ unsigned short Ash[128][40];
    __shared__ unsigned short Asl[128][40];
    __shared__ unsigned short Bsh[128][40];
    __shared__ unsigned short Bsl[128][40];

    const int t  = threadIdx.x;
    const int w  = t >> 6;
    const int l  = t & 63;
    const int o0 = blockIdx.x * 128;
    const int m0 = blockIdx.y * 128;

    f32x4 acc[2][8];
    #pragma unroll
    for (int r = 0; r < 2; ++r)
        #pragma unroll
        for (int c = 0; c < 8; ++c) acc[r][c] = (f32x4){0.f, 0.f, 0.f, 0.f};

    const int ar = t >> 1, aseg = t & 1;   // A/B staging: row t>>1, 16-short seg
    const int fr = l & 15, kg = l >> 4;

    for (int k0 = 0; k0 < K; k0 += 32) {
        const size_t abase = (size_t)(m0 + ar) * K + k0 + aseg * 16;
        const size_t bbase = (size_t)(o0 + ar) * K + k0 + aseg * 16;
        const bf16x8 ah0 = *reinterpret_cast<const bf16x8*>(&Ahi[abase]);
        const bf16x8 ah1 = *reinterpret_cast<const bf16x8*>(&Ahi[abase + 8]);
        const bf16x8 al0 = *reinterpret_cast<const bf16x8*>(&Alo[abase]);
        const bf16x8 al1 = *reinterpret_cast<const bf16x8*>(&Alo[abase + 8]);
        const bf16x8 bh0 = *reinterpret_cast<const bf16x8*>(&Bhi[bbase]);
        const bf16x8 bh1 = *reinterpret_cast<const bf16x8*>(&Bhi[bbase + 8]);
        const bf16x8 bl0 = *reinterpret_cast<const bf16x8*>(&Blo[bbase]);
        const bf16x8 bl1 = *reinterpret_cast<const bf16x8*>(&Blo[bbase + 8]);
        __syncthreads();
        *reinterpret_cast<bf16x8*>(&Ash[ar][aseg * 16])     = ah0;
        *reinterpret_cast<bf16x8*>(&Ash[ar][aseg * 16 + 8]) = ah1;
        *reinterpret_cast<bf16x8*>(&Asl[ar][aseg * 16])     = al0;
        *reinterpret_cast<bf16x8*>(&Asl[ar][aseg * 16 + 8]) = al1;
        *reinterpret_cast<bf16x8*>(&Bsh[ar][aseg * 16])     = bh0;
        *reinterpret_cast<bf16x8*>(&Bsh[ar][aseg * 16 + 8]) = bh1;
        *reinterpret_cast<bf16x8*>(&Bsl[ar][aseg * 16])     = bl0;
        *reinterpret_cast<bf16x8*>(&Bsl[ar][aseg * 16 + 8]) = bl1;
        __syncthreads();

        // two column-chunks of 4 to cap register pressure
        #pragma unroll
        for (int cc = 0; cc < 2; ++cc) {
            bf16x8 bfh[4], bfl[4];
            #pragma unroll
            for (int c = 0; c < 4; ++c) {
                bfh[c] = *reinterpret_cast<const bf16x8*>(&Bsh[(cc * 4 + c) * 16 + fr][kg * 8]);
                bfl[c] = *reinterpret_cast<const bf16x8*>(&Bsl[(cc * 4 + c) * 16 + fr][kg * 8]);
            }
            #pragma unroll
            for (int r = 0; r < 2; ++r) {
                const bf16x8 afh = *reinterpret_cast<const bf16x8*>(&Ash[w * 32 + r * 16 + fr][kg * 8]);
                const bf16x8 afl = *reinterpret_cast<const bf16x8*>(&Asl[w * 32 + r * 16 + fr][kg * 8]);
                #pragma unroll
                for (int c = 0; c < 4; ++c) {
                    f32x4 a = acc[r][cc * 4 + c];
                    a = __builtin_amdgcn_mfma_f32_16x16x32_bf16(afh, bfh[c], a, 0, 0, 0);
                    a = __builtin_amdgcn_mfma_f32_16x16x32_bf16(afh, bfl[c], a, 0, 0, 0);
                    a = __builtin_amdgcn_mfma_f32_16x16x32_bf16(afl, bfh[c], a, 0, 0, 0);
                    a = __builtin_amdgcn_mfma_f32_16x16x32_bf16(afl, bfl[c], a, 0, 0, 0);
                    acc[r][cc * 4 + c] = a;
                }
            }
        }
    }

    #pragma unroll
    for (int c = 0; c < 8; ++c) {
        int oo = o0 + c * 16 + fr;
        float* dst = (oo < 1024) ? outq : outk;
        oo &= 1023;
        const int hh = oo >> 6, d0 = oo & 63;
        #pragma unroll
        for (int r = 0; r < 2; ++r) {
            #pragma unroll
            for (int j = 0; j < 4; ++j) {
                const int m = m0 + w * 32 + r * 16 + kg * 4 + j;
                const int bb_ = m >> 10, n = m & 1023;
                dst[((((size_t)bb_ * H_) + hh) * N_ + n) * HD_ + d0] = acc[r][c][j];
            }
        }
    }
}

// ---------------------------------------------------------------------------
// bf16 MFMA GEMM (damped paths). r19: O-tile 128 (halves B/A HBM re-reads).
// Per-output accumulation order identical to r13 (bit-identical).
// ---------------------------------------------------------------------------
template<int OUT_BF16>
__global__ __launch_bounds__(256)
void mfma_gemm_kernel(const unsigned short* __restrict__ A,
                      const unsigned short* __restrict__ Bw,
                      const float* __restrict__ bias,
                      float* __restrict__ outF,
                      unsigned short* __restrict__ outB,
                      int M, int O, int K)
{
    __shared__ unsigned short As[128][40];
    __shared__ unsigned short Bs[128][40];

    const int t  = threadIdx.x;
    const int w  = t >> 6;
    const int l  = t & 63;
    const int o0 = blockIdx.x * 128;
    const int m0 = blockIdx.y * 128;
    const size_t zoff = (size_t)blockIdx.z * 1048576;
    Bw += zoff;

    f32x4 acc[2][8];
    #pragma unroll
    for (int r = 0; r < 2; ++r)
        #pragma unroll
        for (int c = 0; c < 8; ++c) acc[r][c] = (f32x4){0.f, 0.f, 0.f, 0.f};

    const int ar = t >> 1, aseg = t & 1;
    const int fr = l & 15, kg = l >> 4;

    for (int k0 = 0; k0 < K; k0 += 32) {
        const size_t abase = (size_t)(m0 + ar) * K + k0 + aseg * 16;
        const size_t bbase = (size_t)(o0 + ar) * K + k0 + aseg * 16;
        const bf16x8 a0 = *reinterpret_cast<const bf16x8*>(&A[abase]);
        const bf16x8 a1 = *reinterpret_cast<const bf16x8*>(&A[abase + 8]);
        const bf16x8 b0 = *reinterpret_cast<const bf16x8*>(&Bw[bbase]);
        const bf16x8 b1 = *reinterpret_cast<const bf16x8*>(&Bw[bbase + 8]);
        __syncthreads();
        *reinterpret_cast<bf16x8*>(&As[ar][aseg * 16])     = a0;
        *reinterpret_cast<bf16x8*>(&As[ar][aseg * 16 + 8]) = a1;
        *reinterpret_cast<bf16x8*>(&Bs[ar][aseg * 16])     = b0;
        *reinterpret_cast<bf16x8*>(&Bs[ar][aseg * 16 + 8]) = b1;
        __syncthreads();

        #pragma unroll
        for (int cc = 0; cc < 2; ++cc) {
            bf16x8 bfr[4];
            #pragma unroll
            for (int c = 0; c < 4; ++c)
                bfr[c] = *reinterpret_cast<const bf16x8*>(&Bs[(cc * 4 + c) * 16 + fr][kg * 8]);
            #pragma unroll
            for (int r = 0; r < 2; ++r) {
                const bf16x8 af = *reinterpret_cast<const bf16x8*>(&As[w * 32 + r * 16 + fr][kg * 8]);
                #pragma unroll
                for (int c = 0; c < 4; ++c)
                    acc[r][cc * 4 + c] = __builtin_amdgcn_mfma_f32_16x16x32_bf16(af, bfr[c], acc[r][cc * 4 + c], 0, 0, 0);
            }
        }
    }

    #pragma unroll
    for (int c = 0; c < 8; ++c) {
        const int col = o0 + c * 16 + fr;
        const float bv = (OUT_BF16 == 0) ? bias[col] : 0.f;
        #pragma unroll
        for (int r = 0; r < 2; ++r) {
            #pragma unroll
            for (int j = 0; j < 4; ++j) {
                const int row = m0 + w * 32 + r * 16 + kg * 4 + j;
                const float v = acc[r][c][j] + bv;
                if (OUT_BF16)
                    outB[zoff + (size_t)row * O + col] = f2bf(v);
                else
                    outF[(size_t)row * O + col] = v;
            }
        }
    }
}

// ---------------------------------------------------------------------------
__global__ void wsum_kernel(const float* __restrict__ W_v, double* __restrict__ wsh)
{
    const int k = blockIdx.x * 256 + threadIdx.x;
    const int h = blockIdx.y;
    double s = 0.0;
    #pragma unroll 8
    for (int d = 0; d < 64; ++d) s += (double)W_v[(size_t)(h * 64 + d) * C_ + k];
    wsh[h * C_ + k] = s;
}

__global__ __launch_bounds__(256)
void vall_kernel(const float* __restrict__ x, const double* __restrict__ wsh,
                 double* __restrict__ Vall)
{
    __shared__ double ws_s[1024];
    const int h = blockIdx.y, b = blockIdx.z;
    const int m = blockIdx.x * 256 + threadIdx.x;
    for (int i = threadIdx.x; i < 1024; i += 256) ws_s[i] = wsh[h * C_ + i];
    __syncthreads();
    const float* xr = x + ((size_t)b * N_ + m) * C_;
    double acc = 0.0;
    #pragma unroll 8
    for (int kk = 0; kk < 1024; ++kk) acc += (double)xr[kk] * ws_s[kk];
    Vall[((size_t)b * H_ + h) * N_ + m] = acc;
}

// ---------------------------------------------------------------------------
// Fused attention — EXACT r16 kernel (best measured: 403us, absmax 96).
// ---------------------------------------------------------------------------
__device__ __forceinline__ f32x2 pk_fma(f32x2 a, f32x2 b, f32x2 c) {
#if __has_builtin(__builtin_elementwise_fma)
    return __builtin_elementwise_fma(a, b, c);
#else
    f32x2 r; r.x = fmaf(a.x, b.x, c.x); r.y = fmaf(a.y, b.y, c.y); return r;
#endif
}

__global__ __launch_bounds__(256)
void attn_kernel(const float* __restrict__ q,
                 const float* __restrict__ k,
                 const unsigned short* __restrict__ vtb,
                 const double* __restrict__ Vall,
                 const float* __restrict__ coord,
                 const float* __restrict__ W_pos,
                 const float* __restrict__ gating,
                 unsigned short* __restrict__ attnB)
{
    __shared__ float4 Qs4[16][16];                          // 4096B
    __shared__ float4 Kt4[64][16];                          // 16384B
    __shared__ __align__(16) unsigned short ptB[16 * 64];   // 2048B (epi alias)
    __shared__ __align__(16) unsigned short qtB[16 * 64];   // 2048B
    __shared__ __align__(16) unsigned short VtB[2][64 * 64];// 16384B

    const int t  = threadIdx.x;
    const int w  = t >> 6;
    const int l  = t & 63;
    const int n0 = blockIdx.x * 16;
    const int h  = blockIdx.y;
    const int b  = blockIdx.z;
    const size_t bhN = ((size_t)b * H_ + h) * N_;

    const int sr0 = t >> 4;
    const int sc  = t & 15;
    const int vd  = t >> 2;
    const int vkc = (t & 3) * 16;
    const unsigned short* vrow = vtb + (((size_t)b * H_ + h) * 64 + vd) * N_;
    const int vswz = (vd & 7) << 4;

    Qs4[t >> 4][t & 15] = reinterpret_cast<const float4*>(q + (bhN + n0) * HD_)[t];

    float qcx[4], qcy[4], qcz[4];
    #pragma unroll
    for (int i = 0; i < 4; ++i) {
        const float* cp = coord + ((size_t)b * N_ + n0 + w + 4 * i) * 3;
        qcx[i] = rdfl(cp[0]);
        qcy[i] = rdfl(cp[1]);
        qcz[i] = rdfl(cp[2]);
    }
    const double w4hd = (double)W_pos[h * 4 + 3];
    const double ghd  = 1.0 / (1.0 + exp(-(double)gating[h]));

    double sp[4], sq[4], spv[4], sqv[4];
    f32x4 accP = {0.f, 0.f, 0.f, 0.f};
    f32x4 accQ = {0.f, 0.f, 0.f, 0.f};
    #pragma unroll
    for (int i = 0; i < 4; ++i) { sp[i] = 0.0; sq[i] = 0.0; spv[i] = 0.0; sqv[i] = 0.0; }

    {
        const float4* kb4 = reinterpret_cast<const float4*>(k + bhN * HD_);
        #pragma unroll
        for (int i = 0; i < 4; ++i)
            Kt4[sr0 + i * 16][sc ^ ((sr0 + i * 16) & 15)] = kb4[t + i * 256];
        const bf16x8 v0 = *reinterpret_cast<const bf16x8*>(vrow + vkc);
        const bf16x8 v1 = *reinterpret_cast<const bf16x8*>(vrow + vkc + 8);
        char* vb = reinterpret_cast<char*>(&VtB[0][0]);
        *reinterpret_cast<bf16x8*>(vb + ((vd * 128 + vkc * 2)      ^ vswz)) = v0;
        *reinterpret_cast<bf16x8*>(vb + ((vd * 128 + vkc * 2 + 16) ^ vswz)) = v1;
    }
    double Vm  = Vall[bhN + l];
    double cmx = (double)coord[((size_t)b * N_ + l) * 3 + 0];
    double cmy = (double)coord[((size_t)b * N_ + l) * 3 + 1];
    double cmz = (double)coord[((size_t)b * N_ + l) * 3 + 2];
    __syncthreads();

    for (int t16 = 0; t16 < 16; ++t16) {
        const int m0   = t16 * 64;
        const int vcur = t16 & 1;

        float4 st0, st1, st2, st3;
        bf16x8 sv0, sv1;
        double VmN = 0.0, cmxN = 0.0, cmyN = 0.0, cmzN = 0.0;
        if (t16 < 15) {
            const float4* kb4 = reinterpret_cast<const float4*>(k + (bhN + m0 + 64) * HD_);
            st0 = kb4[t];
            st1 = kb4[t + 256];
            st2 = kb4[t + 512];
            st3 = kb4[t + 768];
            sv0 = *reinterpret_cast<const bf16x8*>(vrow + m0 + 64 + vkc);
            sv1 = *reinterpret_cast<const bf16x8*>(vrow + m0 + 64 + vkc + 8);
            VmN  = Vall[bhN + m0 + 64 + l];
            cmxN = (double)coord[((size_t)b * N_ + m0 + 64 + l) * 3 + 0];
            cmyN = (double)coord[((size_t)b * N_ + m0 + 64 + l) * 3 + 1];
            cmzN = (double)coord[((size_t)b * N_ + m0 + 64 + l) * 3 + 2];
        }

        f32x2 dot2[4][2];
        #pragma unroll
        for (int i = 0; i < 4; ++i) {
            dot2[i][0] = (f32x2){0.f, 0.f};
            dot2[i][1] = (f32x2){0.f, 0.f};
        }
        #pragma unroll
        for (int d4 = 0; d4 < 16; ++d4) {
            const float4 kt = Kt4[l][d4 ^ (l & 15)];
            const int g = d4 >> 3;
            const f32x2 kxy = {kt.x, kt.y};
            const f32x2 kzw = {kt.z, kt.w};
            #pragma unroll
            for (int i = 0; i < 4; ++i) {
                const float4 q4 = Qs4[w + 4 * i][d4];
                dot2[i][g] = pk_fma(kxy, (f32x2){q4.x, q4.y}, dot2[i][g]);
                dot2[i][g] = pk_fma(kzw, (f32x2){q4.z, q4.w}, dot2[i][g]);
            }
        }

        #pragma unroll
        for (int i = 0; i < 4; ++i) {
            const int r = w + 4 * i;
            const double lgs = (((double)dot2[i][0].x + (double)dot2[i][0].y) +
                                ((double)dot2[i][1].x + (double)dot2[i][1].y));
            const float pf = fast_exp2f((float)(lgs * 0.18033688011112042));  // 0.125*log2(e)
            const double dx = (double)qcx[i] - cmx;
            const double dy = (double)qcy[i] - cmy;
            const double dz = (double)qcz[i] - cmz;
            const double r2 = __fma_rn(dx, dx, __fma_rn(dy, dy, dz * dz));
            const double y0 = (double)rsqrtf((float)r2);
            const double y1 = y0 * __fma_rn(-0.5 * r2, y0 * y0, 1.5);
            const double dist = (r2 > 0.0) ? r2 * y1 : 0.0;
            const double q64 = fast_exp64(dist * w4hd);
            const int off = (r * 128 + l * 2) ^ ((r & 7) << 4);
            *reinterpret_cast<unsigned short*>(reinterpret_cast<char*>(ptB) + off) = f2bf(pf);
            *reinterpret_cast<unsigned short*>(reinterpret_cast<char*>(qtB) + off) = f2bf((float)q64);
            sp[i]  += (double)pf;
            sq[i]  += q64;
            spv[i] += (double)pf * Vm;
            sqv[i] += q64 * Vm;
        }
        __syncthreads();   // barrier A

        {
            const int r_   = l & 15;
            const int kb_  = l >> 4;
            const int aoff = r_ * 128 + kb_ * 16;
            const int aswz = (r_ & 7) << 4;
            const int dimw = w * 16 + r_;
            const int boff = dimw * 128 + kb_ * 16;
            const int bswz = (dimw & 7) << 4;
            const char* pbase = reinterpret_cast<const char*>(ptB);
            const char* qbase = reinterpret_cast<const char*>(qtB);
            const char* vbase = reinterpret_cast<const char*>(&VtB[vcur][0]);
            #pragma unroll
            for (int kh = 0; kh < 2; ++kh) {
                const bf16x8 afp = *reinterpret_cast<const bf16x8*>(pbase + ((aoff + kh * 64) ^ aswz));
                const bf16x8 afq = *reinterpret_cast<const bf16x8*>(qbase + ((aoff + kh * 64) ^ aswz));
                const bf16x8 bf_ = *reinterpret_cast<const bf16x8*>(vbase + ((boff + kh * 64) ^ bswz));
                accP = __builtin_amdgcn_mfma_f32_16x16x32_bf16(afp, bf_, accP, 0, 0, 0);
                accQ = __builtin_amdgcn_mfma_f32_16x16x32_bf16(afq, bf_, accQ, 0, 0, 0);
            }
        }

        if (t16 < 15) {
            Kt4[sr0     ][sc ^ ( sr0       & 15)] = st0;
            Kt4[sr0 + 16][sc ^ ((sr0 + 16) & 15)] = st1;
            Kt4[sr0 + 32][sc ^ ((sr0 + 32) & 15)] = st2;
            Kt4[sr0 + 48][sc ^ ((sr0 + 48) & 15)] = st3;
            char* vb = reinterpret_cast<char*>(&VtB[vcur ^ 1][0]);
            *reinterpret_cast<bf16x8*>(vb + ((vd * 128 + vkc * 2)      ^ vswz)) = sv0;
            *reinterpret_cast<bf16x8*>(vb + ((vd * 128 + vkc * 2 + 16) ^ vswz)) = sv1;
            Vm = VmN; cmx = cmxN; cmy = cmyN; cmz = cmzN;
        }
        __syncthreads();   // barrier B  (frees ptB for epilogue alias)
    }

    double* epi = reinterpret_cast<double*>(ptB);
    #pragma unroll
    for (int i = 0; i < 4; ++i) {
        double vsp = sp[i], vsq = sq[i], vspv = spv[i], vsqv = sqv[i];
        #pragma unroll
        for (int mm = 32; mm >= 1; mm >>= 1) {
            vsp  += __shfl_xor(vsp,  mm);
            vsq  += __shfl_xor(vsq,  mm);
            vspv += __shfl_xor(vspv, mm);
            vsqv += __shfl_xor(vsqv, mm);
        }
        const double w1 = (1.0 - ghd) / vsp;
        const double w2 = ghd / vsq;
        if (l == 0) {
            epi[w + 4 * i]      = w1;
            epi[16 + w + 4 * i] = w2;
            epi[32 + w + 4 * i] = w1 * vspv + w2 * vsqv;   // S
        }
    }
    __syncthreads();
    const int col = h * HD_ + w * 16 + (l & 15);
    #pragma unroll
    for (int j = 0; j < 4; ++j) {
        const int m = 4 * (l >> 4) + j;
        const double a = epi[m] * (double)accP[j] + epi[16 + m] * (double)accQ[j];
        attnB[((size_t)b * N_ + n0 + m) * C_ + col] = f2bf((float)(a / epi[32 + m]));
    }
}

// ---------------------------------------------------------------------------
extern "C" void kernel_launch(void* const* d_in, const int* in_sizes, int n_in,
                              void* d_out, int out_size, void* d_ws, size_t ws_size,
                              hipStream_t stream)
{
    const float* x      = (const float*)d_in[0];
    const float* coord  = (const float*)d_in[1];
    const float* W_qk   = (const float*)d_in[2];
    const float* W_v    = (const float*)d_in[3];
    const float* W_proj = (const float*)d_in[4];
    const float* b_proj = (const float*)d_in[5];
    const float* W_pos  = (const float*)d_in[6];
    // d_in[7] = b_pos (cancels in softmax), d_in[9] = pos_emb (cancels) — unused
    const float* gating = (const float*)d_in[8];

    float* ws   = (float*)d_ws;
    const size_t per = (size_t)B_ * H_ * N_ * HD_;   // 4,194,304 elements
    float*          qb    = ws;                          // 16MB
    float*          kb    = qb + per;                    // 16MB
    unsigned short* attnB = (unsigned short*)(kb + per); // 8MB; hosts Wqk splits pre-attn
    unsigned short* WqkHi = attnB;                       // 4MB
    unsigned short* WqkLo = attnB + 2 * (size_t)C_ * C_; // 4MB
    unsigned short* vtb   = attnB + per;                 // 8MB
    unsigned short* xhi   = vtb + per;                   // 8MB (also v-GEMM's A)
    unsigned short* xlo   = xhi + per;                   // 8MB
    unsigned short* WvB   = xlo + per;                   // 2MB
    unsigned short* WpB   = WvB + (size_t)C_ * C_;       // 2MB
    double*         wsh   = (double*)(WpB + (size_t)C_ * C_);
    double*         Vall  = wsh + (size_t)H_ * C_;
    float*          out   = (float*)d_out;

    // splits + bf16 conversions
    cvt_split_kernel<<<2048, 256, 0, stream>>>(x, xhi, xlo, (int)per);
    cvt_split_kernel<<<1024, 256, 0, stream>>>(W_qk, WqkHi, WqkLo, 2 * C_ * C_);
    cvt_bf16_kernel<<<512, 256, 0, stream>>>(W_v, WvB, C_ * C_);
    cvt_bf16_kernel<<<512, 256, 0, stream>>>(W_proj, WpB, C_ * C_);

    // exact S-path precomputation (from raw f32 inputs)
    wsum_kernel<<<dim3(4, 16), 256, 0, stream>>>(W_v, wsh);
    vall_kernel<<<dim3(4, 16, 4), 256, 0, stream>>>(x, wsh, Vall);

    // q,k via split-bf16 MFMA (O-tile 128)
    qk_split_kernel<<<dim3(16, 32), 256, 0, stream>>>(
        xhi, xlo, WqkHi, WqkLo, qb, kb, B_ * N_, 2 * C_, C_);

    // v^T bf16 via MFMA (O-tile 128)
    mfma_gemm_kernel<1><<<dim3(8, 8, 4), 256, 0, stream>>>(
        WvB, xhi, nullptr, nullptr, vtb, C_, N_, C_);

    // fused attention (r16, best)
    attn_kernel<<<dim3(N_ / 16, H_, B_), 256, 0, stream>>>(
        qb, kb, vtb, Vall, coord, W_pos, gating, attnB);

    // proj via MFMA (O-tile 128)
    mfma_gemm_kernel<0><<<dim3(8, 32, 1), 256, 0, stream>>>(
        attnB, WpB, b_proj, out, nullptr, B_ * N_, C_, C_);
}